// Round 8
// baseline (383.472 us; speedup 1.0000x reference)
//
#include <hip/hip_runtime.h>

#define B_ 2
#define N_ 2048
#define D_ 1024
#define H_ 16
#define DH_ 64
#define NITEMS 1024  // (B*H) * (N/64) q-tiles

typedef _Float16 half8 __attribute__((ext_vector_type(8)));
typedef _Float16 half4 __attribute__((ext_vector_type(4)));
typedef float f32x4 __attribute__((ext_vector_type(4)));

__device__ __forceinline__ void gl2lds16(const _Float16* g, _Float16* l) {
  __builtin_amdgcn_global_load_lds(
      (const __attribute__((address_space(1))) void*)g,
      (__attribute__((address_space(3))) void*)l, 16, 0, 0);
}

// ---------------------------------------------------------------------------
// Fused prep: [0,6144) convert q/k/v fp32->fp16; [6144,7168) convert+transpose
// weights to fp16 W^T; [7168] rank heads by valid_len desc (LPT order).
__global__ __launch_bounds__(256) void prep_kernel(
    const float* __restrict__ q, const float* __restrict__ k,
    const float* __restrict__ v, const float* __restrict__ Wq,
    const float* __restrict__ Wk, const float* __restrict__ Wv,
    const float* __restrict__ Wo, const int* __restrict__ vlen,
    _Float16* __restrict__ Xf, _Float16* __restrict__ WtAll,
    int* __restrict__ order) {
  __shared__ float tile[64][65];
  const int bid = blockIdx.x;
  if (bid < 6144) {
    int y = bid >> 11, x = bid & 2047;
    const float* s = (y == 0) ? q : (y == 1) ? k : v;
    _Float16* d = Xf + (size_t)y * ((size_t)B_ * N_ * D_);
    size_t idx = ((size_t)x * 256 + threadIdx.x) * 8;
    float4 a = *(const float4*)(s + idx);
    float4 b = *(const float4*)(s + idx + 4);
    half8 h;
    h[0] = (_Float16)a.x; h[1] = (_Float16)a.y; h[2] = (_Float16)a.z; h[3] = (_Float16)a.w;
    h[4] = (_Float16)b.x; h[5] = (_Float16)b.y; h[6] = (_Float16)b.z; h[7] = (_Float16)b.w;
    *(half8*)(d + idx) = h;
  } else if (bid < 6144 + 1024) {
    int idx = bid - 6144;
    int z = idx >> 8, rem = idx & 255, gy = rem >> 4, gx = rem & 15;
    const float* W = (z == 0) ? Wq : (z == 1) ? Wk : (z == 2) ? Wv : Wo;
    _Float16* Wt = WtAll + (size_t)z * D_ * D_;
    int k0 = gy * 64, n0 = gx * 64;
    int tr = threadIdx.x >> 4, tc = threadIdx.x & 15;
#pragma unroll
    for (int i = 0; i < 4; ++i) {
      int r = tr + i * 16;
      float4 va = *(const float4*)(W + (size_t)(k0 + r) * D_ + n0 + tc * 4);
      tile[r][tc * 4 + 0] = va.x; tile[r][tc * 4 + 1] = va.y;
      tile[r][tc * 4 + 2] = va.z; tile[r][tc * 4 + 3] = va.w;
    }
    __syncthreads();
#pragma unroll
    for (int i = 0; i < 4; ++i) {
      int r = tr + i * 16;
      half4 hv;
      hv[0] = (_Float16)tile[tc * 4 + 0][r];
      hv[1] = (_Float16)tile[tc * 4 + 1][r];
      hv[2] = (_Float16)tile[tc * 4 + 2][r];
      hv[3] = (_Float16)tile[tc * 4 + 3][r];
      *(half4*)(Wt + (size_t)(n0 + r) * D_ + k0 + tc * 4) = hv;
    }
  } else {
    int i = threadIdx.x;
    if (i < B_ * H_) {
      int vi = vlen[i], rank = 0;
      for (int j = 0; j < B_ * H_; ++j) {
        int vj = vlen[j];
        if (vj > vi || (vj == vi && j < i)) ++rank;
      }
      order[rank] = i;
    }
  }
}

// ---------------------------------------------------------------------------
// fp16 MFMA GEMM (R2-proven structure): BK=32, single-buffer, 16 MFMA/barrier.
// C[128 x BN] tiles, K=1024.
// MODE 0: z=0 -> Q head-split; z=1 -> K head-split;
//         z=2 -> V^T [bh][dh][key] (transpose folded in).
// MODE 1: fp32 out.
#define BK 32

template <int NT, int MODE>
__global__ __launch_bounds__(256) void gemm_f16_kernel(
    const _Float16* __restrict__ Aall, const _Float16* __restrict__ Btall,
    _Float16* __restrict__ ChAll, float* __restrict__ Cf32) {
  constexpr int BN = NT * 32;
  constexpr int K = D_;
  __shared__ __attribute__((aligned(16))) _Float16 As[128 * BK];
  __shared__ __attribute__((aligned(16))) _Float16 Bs[BN * BK];
  const int z = blockIdx.z;
  const _Float16* A  = Aall  + (size_t)z * ((size_t)B_ * N_ * D_);
  const _Float16* Bt = Btall + (size_t)z * ((size_t)D_ * D_);
  _Float16* Chead = ChAll + (size_t)z * ((size_t)B_ * N_ * D_);

  const int tid = threadIdx.x;
  const int m0 = blockIdx.y * 128, n0 = blockIdx.x * BN;
  const int lane = tid & 63, w = tid >> 6;
  const int quad = lane >> 4, l15 = lane & 15;
  const int wm = (w >> 1) * 64, wn = (w & 1) * (BN / 2);
  const int swz = (quad ^ ((l15 >> 1) & 3)) * 8;
  f32x4 acc[4][NT] = {};

  for (int kt = 0; kt < K; kt += BK) {
    if (kt) __syncthreads();
#pragma unroll
    for (int p = 0; p < 2; ++p) {
      int c = p * 256 + tid;
      int row = c >> 2, pg = c & 3;
      int gl = pg ^ ((row >> 1) & 3);
      gl2lds16(A + (size_t)(m0 + row) * K + kt + gl * 8, &As[c * 8]);
    }
#pragma unroll
    for (int p = 0; p < NT / 2; ++p) {
      int c = p * 256 + tid;
      int row = c >> 2, pg = c & 3;
      int gl = pg ^ ((row >> 1) & 3);
      gl2lds16(Bt + (size_t)(n0 + row) * K + kt + gl * 8, &Bs[c * 8]);
    }
    __syncthreads();
    half8 af[4], bf[NT];
#pragma unroll
    for (int mt = 0; mt < 4; ++mt)
      af[mt] = *(const half8*)&As[(wm + mt * 16 + l15) * 32 + swz];
#pragma unroll
    for (int nt = 0; nt < NT; ++nt)
      bf[nt] = *(const half8*)&Bs[(wn + nt * 16 + l15) * 32 + swz];
#pragma unroll
    for (int mt = 0; mt < 4; ++mt)
#pragma unroll
      for (int nt = 0; nt < NT; ++nt)
        acc[mt][nt] = __builtin_amdgcn_mfma_f32_16x16x32_f16(
            af[mt], bf[nt], acc[mt][nt], 0, 0, 0);
  }

#pragma unroll
  for (int mt = 0; mt < 4; ++mt) {
    int mrow = m0 + wm + mt * 16 + quad * 4;
#pragma unroll
    for (int nt = 0; nt < NT; ++nt) {
      int jcol = n0 + wn + nt * 16 + l15;
      if (MODE == 0) {
        int b = mrow >> 11, n = mrow & (N_ - 1);
        int h = jcol >> 6, dh = jcol & (DH_ - 1);
        if (z == 2) {
          // V^T layout [bh][dh][key]; 4 acc rows = 4 consecutive keys.
          half4 o;
#pragma unroll
          for (int r = 0; r < 4; ++r) o[r] = (_Float16)acc[mt][nt][r];
          *(half4*)(ChAll + 2 * (size_t)B_ * N_ * D_ +
                    ((size_t)(b * H_ + h) * DH_ + dh) * N_ + n) = o;
        } else {
#pragma unroll
          for (int r = 0; r < 4; ++r)
            Chead[((((size_t)(b * H_ + h)) * N_ + n + r) * DH_) + dh] =
                (_Float16)acc[mt][nt][r];
        }
      } else {
#pragma unroll
        for (int r = 0; r < 4; ++r)
          Cf32[(size_t)(mrow + r) * D_ + jcol] = acc[mt][nt][r];
      }
    }
  }
}

// ---------------------------------------------------------------------------
// Flash attention v3: R0 work decomposition (wave owns 16 q x all 64 keys of
// each step), identity item map (co-resident blocks = same head -> shared K/V
// stream, proven best R0 vs R2/R4/R6), but ZERO LDS and ZERO barriers:
// K and V^T fragments load global->register at the exact offsets the old LDS
// path produced (XOR store/read swizzles cancel; operand values identical).
// K: 16 contiguous rows x 64 B per load pair = well coalesced. V: 32-B chunks,
// but all 16 waves/CU read the same 24 KB/step -> L1-resident. Removes the
// 2-barrier lockstep + LDS round-trip that dominated t_step (R0 evidence:
// 1.6 us/epoch vs ~0.45 issue-bound; R4: memory proven non-binding).
__global__ __launch_bounds__(256, 4) void attn_kernel(
    const _Float16* __restrict__ Qh, const _Float16* __restrict__ Kh,
    const _Float16* __restrict__ VtG, const int* __restrict__ vlen,
    _Float16* __restrict__ Hd, const int* __restrict__ order) {
  const int tid = threadIdx.x, lane = tid & 63, w = tid >> 6;
  const int quad = lane >> 4, l15 = lane & 15;
  const float sc2 = 0.125f * 1.44269504088896f;  // (1/sqrt(64))*log2(e)
  const half4 ones = {(_Float16)1, (_Float16)1, (_Float16)1, (_Float16)1};

  const int item = blockIdx.x;  // identity: co-resident = same head
  const int bh = order[item >> 5];
  const int q0 = (item & 31) * 64;
  const int b = bh >> 4, h = bh & (H_ - 1);
  const int vl = vlen[bh];
  const int KT = (vl + 63) >> 6;
  const _Float16* Qb = Qh  + (size_t)bh * N_ * DH_;
  const _Float16* Kb = Kh  + (size_t)bh * N_ * DH_;
  const _Float16* Vb = VtG + (size_t)bh * N_ * DH_;  // [dh][key], row stride N_

  // wave's 16 q rows, both dh halves (8 VGPR)
  const half8 qb0 = *(const half8*)(Qb + (size_t)(q0 + w * 16 + l15) * DH_ + quad * 8);
  const half8 qb1 = *(const half8*)(Qb + (size_t)(q0 + w * 16 + l15) * DH_ + 32 + quad * 8);

  // loop-invariant lane bases
  const _Float16* krow = Kb + (size_t)l15 * DH_ + quad * 8;  // + (k0k+nt*16)*DH_
  const _Float16* vrow = Vb + (size_t)l15 * N_ + quad * 4;   // + dt*16*N_ + k0k + nt*16

  f32x4 Oacc[4] = {};
  f32x4 lacc = {};

  for (int kt = 0; kt < KT; ++kt) {
    const int k0k = kt * 64;

    // V^T fragments first (consumed last -> max latency slack).
    // va[dt][nt]: dh = dt*16 + l15, keys = nt*16 + quad*4 .. +3
    half4 va[4][4];
#pragma unroll
    for (int dt = 0; dt < 4; ++dt)
#pragma unroll
      for (int nt = 0; nt < 4; ++nt)
        va[dt][nt] = *(const half4*)(vrow + (size_t)dt * 16 * N_ + k0k + nt * 16);

    // S^T = K·Q^T : rows = key (nt*16 + quad*4 + r), cols = q (l15)
    f32x4 s[4];
#pragma unroll
    for (int nt = 0; nt < 4; ++nt) {
      const _Float16* kp = krow + (size_t)(k0k + nt * 16) * DH_;
      half8 ka0 = *(const half8*)kp;
      half8 ka1 = *(const half8*)(kp + 32);
      f32x4 c = {};
      c = __builtin_amdgcn_mfma_f32_16x16x32_f16(ka0, qb0, c, 0, 0, 0);
      c = __builtin_amdgcn_mfma_f32_16x16x32_f16(ka1, qb1, c, 0, 0, 0);
      s[nt] = c;
    }

    // no-max softmax: p = exp2(s*scale*log2e); masked -> 0
    half4 pf[4];
    if (k0k + 64 <= vl) {
#pragma unroll
      for (int nt = 0; nt < 4; ++nt)
#pragma unroll
        for (int r = 0; r < 4; ++r)
          pf[nt][r] = (_Float16)exp2f(s[nt][r] * sc2);
    } else {
#pragma unroll
      for (int nt = 0; nt < 4; ++nt) {
        int keyb = k0k + nt * 16 + quad * 4;
#pragma unroll
        for (int r = 0; r < 4; ++r) {
          float p = exp2f(s[nt][r] * sc2);
          pf[nt][r] = (keyb + r < vl) ? (_Float16)p : (_Float16)0.f;
        }
      }
    }

    // O^T += V^T·P^T ; l += ones·P^T (row-sum on MFMA pipe)
#pragma unroll
    for (int nt = 0; nt < 4; ++nt) {
      lacc = __builtin_amdgcn_mfma_f32_16x16x16f16(ones, pf[nt], lacc, 0, 0, 0);
#pragma unroll
      for (int dt = 0; dt < 4; ++dt)
        Oacc[dt] = __builtin_amdgcn_mfma_f32_16x16x16f16(va[dt][nt], pf[nt], Oacc[dt], 0, 0, 0);
    }
  }

  // epilogue: O^T[dh][q] -> Hd[(b,q), h*64+dh], fp16 (R0-identical)
  float inv_l = 1.0f / lacc[0];
  int q = q0 + w * 16 + l15;
  _Float16* out = Hd + ((size_t)(b * N_ + q)) * D_ + h * DH_;
#pragma unroll
  for (int dt = 0; dt < 4; ++dt) {
    half4 o;
#pragma unroll
    for (int r = 0; r < 4; ++r) o[r] = (_Float16)(Oacc[dt][r] * inv_l);
    *(half4*)(out + dt * 16 + quad * 4) = o;
  }
}

// ---------------------------------------------------------------------------
extern "C" void kernel_launch(void* const* d_in, const int* in_sizes, int n_in,
                              void* d_out, int out_size, void* d_ws, size_t ws_size,
                              hipStream_t stream) {
  const float* q  = (const float*)d_in[0];
  const float* k  = (const float*)d_in[1];
  const float* v  = (const float*)d_in[2];
  const int*   vl = (const int*)d_in[3];
  const float* Wq = (const float*)d_in[4];
  const float* Wk = (const float*)d_in[5];
  const float* Wv = (const float*)d_in[6];
  const float* Wo = (const float*)d_in[7];

  const size_t XSZ = (size_t)B_ * N_ * D_;  // 4M elements
  const size_t WSZ = (size_t)D_ * D_;       // 1M elements
  _Float16* ws = (_Float16*)d_ws;
  _Float16* Xf = ws;                 // 3*XSZ fp16 q,k,v inputs
  _Float16* Wt = Xf + 3 * XSZ;       // 4*WSZ fp16 W^T x4
  _Float16* Qh = Wt + 4 * WSZ;       // 3*XSZ (Qh, Kh, V^T contiguous)
  _Float16* Hd = Qh + 3 * XSZ;       // XSZ
  int* order = (int*)(Hd + XSZ);     // 32-entry LPT head order

  prep_kernel<<<dim3(6144 + 1024 + 1), 256, 0, stream>>>(
      q, k, v, Wq, Wk, Wv, Wo, vl, Xf, Wt, order);

  // fused Q/K/V projections: z selects input/weight/output.
  // z=2 writes V^T directly (transpose folded in).
  gemm_f16_kernel<4, 0><<<dim3(D_ / 128, 32, 3), 256, 0, stream>>>(
      Xf, Wt, Qh, nullptr);

  attn_kernel<<<dim3(NITEMS), 256, 0, stream>>>(
      Qh, Qh + XSZ, Qh + 2 * XSZ, vl, Hd, order);

  // output projection (BN=64 -> 512 blocks, 2/CU)
  gemm_f16_kernel<2, 1><<<dim3(D_ / 64, 32, 1), 256, 0, stream>>>(
      Hd, Wt + 3 * WSZ, nullptr, (float*)d_out);
}

// Round 9
// 220.899 us; speedup vs baseline: 1.7360x; 1.7360x over previous
//
#include <hip/hip_runtime.h>

#define B_ 2
#define N_ 2048
#define D_ 1024
#define H_ 16
#define DH_ 64
#define NITEMS 1024  // (B*H) * (N/64) q-tiles

typedef _Float16 half8 __attribute__((ext_vector_type(8)));
typedef _Float16 half4 __attribute__((ext_vector_type(4)));
typedef float f32x4 __attribute__((ext_vector_type(4)));

__device__ __forceinline__ void gl2lds16(const _Float16* g, _Float16* l) {
  __builtin_amdgcn_global_load_lds(
      (const __attribute__((address_space(1))) void*)g,
      (__attribute__((address_space(3))) void*)l, 16, 0, 0);
}

// ---------------------------------------------------------------------------
// Fused prep: [0,6144) convert q/k/v fp32->fp16; [6144,7168) convert+transpose
// weights to fp16 W^T; [7168] rank heads by valid_len desc (LPT order).
__global__ __launch_bounds__(256) void prep_kernel(
    const float* __restrict__ q, const float* __restrict__ k,
    const float* __restrict__ v, const float* __restrict__ Wq,
    const float* __restrict__ Wk, const float* __restrict__ Wv,
    const float* __restrict__ Wo, const int* __restrict__ vlen,
    _Float16* __restrict__ Xf, _Float16* __restrict__ WtAll,
    int* __restrict__ order) {
  __shared__ float tile[64][65];
  const int bid = blockIdx.x;
  if (bid < 6144) {
    int y = bid >> 11, x = bid & 2047;
    const float* s = (y == 0) ? q : (y == 1) ? k : v;
    _Float16* d = Xf + (size_t)y * ((size_t)B_ * N_ * D_);
    size_t idx = ((size_t)x * 256 + threadIdx.x) * 8;
    float4 a = *(const float4*)(s + idx);
    float4 b = *(const float4*)(s + idx + 4);
    half8 h;
    h[0] = (_Float16)a.x; h[1] = (_Float16)a.y; h[2] = (_Float16)a.z; h[3] = (_Float16)a.w;
    h[4] = (_Float16)b.x; h[5] = (_Float16)b.y; h[6] = (_Float16)b.z; h[7] = (_Float16)b.w;
    *(half8*)(d + idx) = h;
  } else if (bid < 6144 + 1024) {
    int idx = bid - 6144;
    int z = idx >> 8, rem = idx & 255, gy = rem >> 4, gx = rem & 15;
    const float* W = (z == 0) ? Wq : (z == 1) ? Wk : (z == 2) ? Wv : Wo;
    _Float16* Wt = WtAll + (size_t)z * D_ * D_;
    int k0 = gy * 64, n0 = gx * 64;
    int tr = threadIdx.x >> 4, tc = threadIdx.x & 15;
#pragma unroll
    for (int i = 0; i < 4; ++i) {
      int r = tr + i * 16;
      float4 va = *(const float4*)(W + (size_t)(k0 + r) * D_ + n0 + tc * 4);
      tile[r][tc * 4 + 0] = va.x; tile[r][tc * 4 + 1] = va.y;
      tile[r][tc * 4 + 2] = va.z; tile[r][tc * 4 + 3] = va.w;
    }
    __syncthreads();
#pragma unroll
    for (int i = 0; i < 4; ++i) {
      int r = tr + i * 16;
      half4 hv;
      hv[0] = (_Float16)tile[tc * 4 + 0][r];
      hv[1] = (_Float16)tile[tc * 4 + 1][r];
      hv[2] = (_Float16)tile[tc * 4 + 2][r];
      hv[3] = (_Float16)tile[tc * 4 + 3][r];
      *(half4*)(Wt + (size_t)(n0 + r) * D_ + k0 + tc * 4) = hv;
    }
  } else {
    int i = threadIdx.x;
    if (i < B_ * H_) {
      int vi = vlen[i], rank = 0;
      for (int j = 0; j < B_ * H_; ++j) {
        int vj = vlen[j];
        if (vj > vi || (vj == vi && j < i)) ++rank;
      }
      order[rank] = i;
    }
  }
}

// ---------------------------------------------------------------------------
// fp16 MFMA GEMM, NOW 2-PHASE DOUBLE-BUFFERED: stage(tile k+1) overlaps
// compute(tile k); ONE barrier per K-step instead of two (old form fully
// serialized stage->sync->compute, leaving ~400cyc global->LDS latency naked
// on the critical path every 32 steps). Fragment/swizzle algebra unchanged.
// MODE 0: z=0 -> Q head-split; z=1 -> K head-split;
//         z=2 -> V^T [bh][dh][key] (transpose folded in).
// MODE 1: fp32 out.
#define BK 32

template <int NT, int MODE>
__global__ __launch_bounds__(256) void gemm_f16_kernel(
    const _Float16* __restrict__ Aall, const _Float16* __restrict__ Btall,
    _Float16* __restrict__ ChAll, float* __restrict__ Cf32) {
  constexpr int BN = NT * 32;
  constexpr int K = D_;
  constexpr int NSTEP = K / BK;
  __shared__ __attribute__((aligned(16))) _Float16 As[2][128 * BK];
  __shared__ __attribute__((aligned(16))) _Float16 Bs[2][BN * BK];
  const int z = blockIdx.z;
  const _Float16* A  = Aall  + (size_t)z * ((size_t)B_ * N_ * D_);
  const _Float16* Bt = Btall + (size_t)z * ((size_t)D_ * D_);
  _Float16* Chead = ChAll + (size_t)z * ((size_t)B_ * N_ * D_);

  const int tid = threadIdx.x;
  const int m0 = blockIdx.y * 128, n0 = blockIdx.x * BN;
  const int lane = tid & 63, w = tid >> 6;
  const int quad = lane >> 4, l15 = lane & 15;
  const int wm = (w >> 1) * 64, wn = (w & 1) * (BN / 2);
  const int swz = (quad ^ ((l15 >> 1) & 3)) * 8;
  f32x4 acc[4][NT] = {};

  auto stage = [&](int buf, int kt) {
#pragma unroll
    for (int p = 0; p < 2; ++p) {
      int c = p * 256 + tid;
      int row = c >> 2, pg = c & 3;
      int gl = pg ^ ((row >> 1) & 3);
      gl2lds16(A + (size_t)(m0 + row) * K + kt + gl * 8, &As[buf][c * 8]);
    }
#pragma unroll
    for (int p = 0; p < NT / 2; ++p) {
      int c = p * 256 + tid;
      int row = c >> 2, pg = c & 3;
      int gl = pg ^ ((row >> 1) & 3);
      gl2lds16(Bt + (size_t)(n0 + row) * K + kt + gl * 8, &Bs[buf][c * 8]);
    }
  };

  stage(0, 0);
  __syncthreads();  // buf0 ready

  int cur = 0;
  for (int ks = 0; ks < NSTEP; ++ks) {
    if (ks + 1 < NSTEP) stage(cur ^ 1, (ks + 1) * BK);  // overlap with compute
    half8 af[4], bf[NT];
#pragma unroll
    for (int mt = 0; mt < 4; ++mt)
      af[mt] = *(const half8*)&As[cur][(wm + mt * 16 + l15) * 32 + swz];
#pragma unroll
    for (int nt = 0; nt < NT; ++nt)
      bf[nt] = *(const half8*)&Bs[cur][(wn + nt * 16 + l15) * 32 + swz];
#pragma unroll
    for (int mt = 0; mt < 4; ++mt)
#pragma unroll
      for (int nt = 0; nt < NT; ++nt)
        acc[mt][nt] = __builtin_amdgcn_mfma_f32_16x16x32_f16(
            af[mt], bf[nt], acc[mt][nt], 0, 0, 0);
    __syncthreads();  // drains vmcnt -> next buf ready; protects buf reuse
    cur ^= 1;
  }

#pragma unroll
  for (int mt = 0; mt < 4; ++mt) {
    int mrow = m0 + wm + mt * 16 + quad * 4;
#pragma unroll
    for (int nt = 0; nt < NT; ++nt) {
      int jcol = n0 + wn + nt * 16 + l15;
      if (MODE == 0) {
        int b = mrow >> 11, n = mrow & (N_ - 1);
        int h = jcol >> 6, dh = jcol & (DH_ - 1);
        if (z == 2) {
          // V^T layout [bh][dh][key]; 4 acc rows = 4 consecutive keys.
          half4 o;
#pragma unroll
          for (int r = 0; r < 4; ++r) o[r] = (_Float16)acc[mt][nt][r];
          *(half4*)(ChAll + 2 * (size_t)B_ * N_ * D_ +
                    ((size_t)(b * H_ + h) * DH_ + dh) * N_ + n) = o;
        } else {
#pragma unroll
          for (int r = 0; r < 4; ++r)
            Chead[((((size_t)(b * H_ + h)) * N_ + n + r) * DH_) + dh] =
                (_Float16)acc[mt][nt][r];
        }
      } else {
#pragma unroll
        for (int r = 0; r < 4; ++r)
          Cf32[(size_t)(mrow + r) * D_ + jcol] = acc[mt][nt][r];
      }
    }
  }
}

// ---------------------------------------------------------------------------
// Flash attention: EXACT R0 form (proven 50.8us local optimum; every
// alternative tested R2-R8 -- remaps x3, dynamic queue, lgkm-only barrier,
// reg-resident x2 -- was equal or worse). Identity item map: co-resident
// blocks = same head -> shared K/V stream in L1/L2. S^T form, no-max softmax,
// double-buffered K/V LDS, 2-step-ahead register prefetch.
__global__ __launch_bounds__(256, 4) void attn_kernel(
    const _Float16* __restrict__ Qh, const _Float16* __restrict__ Kh,
    const _Float16* __restrict__ VtG, const int* __restrict__ vlen,
    _Float16* __restrict__ Hd, const int* __restrict__ order) {
  __shared__ __attribute__((aligned(16))) _Float16 Ks[2][64 * 64];
  __shared__ __attribute__((aligned(16))) _Float16 Vt[2][64 * 64];
  const int tid = threadIdx.x, lane = tid & 63, w = tid >> 6;
  const int quad = lane >> 4, l15 = lane & 15;
  const int sw  = (quad ^ (l15 & 7)) * 8;
  const int sw2 = ((quad + 4) ^ (l15 & 7)) * 8;
  const float sc2 = 0.125f * 1.44269504088896f;  // (1/sqrt(64))*log2(e)
  const half4 ones = {(_Float16)1, (_Float16)1, (_Float16)1, (_Float16)1};

  const int item = blockIdx.x;
  const int bh = order[item >> 5];
  const int q0 = (item & 31) * 64;
  const int b = bh >> 4, h = bh & (H_ - 1);
  const int vl = vlen[bh];
  const int KT = (vl + 63) >> 6;
  const _Float16* Qb = Qh  + (size_t)bh * N_ * DH_;
  const _Float16* Kb = Kh  + (size_t)bh * N_ * DH_;
  const _Float16* Vb = VtG + (size_t)bh * N_ * DH_;  // [dh][key]

  const half8 qb0 = *(const half8*)(Qb + (size_t)(q0 + w * 16 + l15) * DH_ + quad * 8);
  const half8 qb1 = *(const half8*)(Qb + (size_t)(q0 + w * 16 + l15) * DH_ + 32 + quad * 8);

  half8 kpre[2], vpre[2];
  auto prefetch = [&](int k0k) {
#pragma unroll
    for (int p = 0; p < 2; ++p) {
      int c = p * 256 + tid;
      int row = c >> 3, pg = c & 7;
      kpre[p] = *(const half8*)(Kb + (size_t)(k0k + row) * DH_ + (pg ^ (row & 7)) * 8);
      vpre[p] = *(const half8*)(Vb + (size_t)row * N_ + k0k + pg * 8);
    }
  };
  auto commit = [&](int buf) {
#pragma unroll
    for (int p = 0; p < 2; ++p) {
      int c = p * 256 + tid;
      int row = c >> 3, pg = c & 7;
      *(half8*)&Ks[buf][c * 8] = kpre[p];
      int j0 = (pg * 2) ^ (row & 15), j1 = (pg * 2 + 1) ^ (row & 15);
      half4 lo = {vpre[p][0], vpre[p][1], vpre[p][2], vpre[p][3]};
      half4 hi = {vpre[p][4], vpre[p][5], vpre[p][6], vpre[p][7]};
      *(half4*)&Vt[buf][row * 64 + j0 * 4] = lo;
      *(half4*)&Vt[buf][row * 64 + j1 * 4] = hi;
    }
  };

  prefetch(0);
  commit(0);
  if (KT > 1) prefetch(64);
  __syncthreads();  // buf0 ready

  f32x4 Oacc[4] = {};
  f32x4 lacc = {};

  for (int kt = 0; kt < KT; ++kt) {
    const int cur = kt & 1;
    if (kt + 1 < KT) commit(1 - cur);
    if (kt + 2 < KT) prefetch((kt + 2) * 64);

    // S^T = K·Q^T : rows = key, cols = q (this wave's 16 q)
    f32x4 s[4];
#pragma unroll
    for (int nt = 0; nt < 4; ++nt) {
      int r = nt * 16 + l15;
      half8 ka0 = *(const half8*)&Ks[cur][r * 64 + sw];
      half8 ka1 = *(const half8*)&Ks[cur][r * 64 + sw2];
      f32x4 c = {};
      c = __builtin_amdgcn_mfma_f32_16x16x32_f16(ka0, qb0, c, 0, 0, 0);
      c = __builtin_amdgcn_mfma_f32_16x16x32_f16(ka1, qb1, c, 0, 0, 0);
      s[nt] = c;
    }
    // no-max softmax: p = exp2(s*scale*log2e); masked -> 0
    const int k0k = kt * 64;
    half4 pf[4];
    if (k0k + 64 <= vl) {
#pragma unroll
      for (int nt = 0; nt < 4; ++nt)
#pragma unroll
        for (int r = 0; r < 4; ++r)
          pf[nt][r] = (_Float16)exp2f(s[nt][r] * sc2);
    } else {
#pragma unroll
      for (int nt = 0; nt < 4; ++nt) {
        int keyb = k0k + nt * 16 + quad * 4;
#pragma unroll
        for (int r = 0; r < 4; ++r) {
          float p = exp2f(s[nt][r] * sc2);
          pf[nt][r] = (keyb + r < vl) ? (_Float16)p : (_Float16)0.f;
        }
      }
    }
    // O^T += V^T·P^T ; l += ones·P^T (row-sum on MFMA pipe)
#pragma unroll
    for (int nt = 0; nt < 4; ++nt) {
      lacc = __builtin_amdgcn_mfma_f32_16x16x16f16(ones, pf[nt], lacc, 0, 0, 0);
#pragma unroll
      for (int dt = 0; dt < 4; ++dt) {
        int dh = dt * 16 + l15;
        half4 va = *(const half4*)&Vt[cur][dh * 64 + (((nt * 4 + quad) ^ l15) << 2)];
        Oacc[dt] = __builtin_amdgcn_mfma_f32_16x16x16f16(va, pf[nt], Oacc[dt], 0, 0, 0);
      }
    }
    __syncthreads();  // all waves done with buf[cur]; commits visible
  }

  // epilogue: O^T[dh][q] -> Hd[(b,q), h*64+dh], fp16
  float inv_l = 1.0f / lacc[0];
  int q = q0 + w * 16 + l15;
  _Float16* out = Hd + ((size_t)(b * N_ + q)) * D_ + h * DH_;
#pragma unroll
  for (int dt = 0; dt < 4; ++dt) {
    half4 o;
#pragma unroll
    for (int r = 0; r < 4; ++r) o[r] = (_Float16)(Oacc[dt][r] * inv_l);
    *(half4*)(out + dt * 16 + quad * 4) = o;
  }
}

// ---------------------------------------------------------------------------
extern "C" void kernel_launch(void* const* d_in, const int* in_sizes, int n_in,
                              void* d_out, int out_size, void* d_ws, size_t ws_size,
                              hipStream_t stream) {
  const float* q  = (const float*)d_in[0];
  const float* k  = (const float*)d_in[1];
  const float* v  = (const float*)d_in[2];
  const int*   vl = (const int*)d_in[3];
  const float* Wq = (const float*)d_in[4];
  const float* Wk = (const float*)d_in[5];
  const float* Wv = (const float*)d_in[6];
  const float* Wo = (const float*)d_in[7];

  const size_t XSZ = (size_t)B_ * N_ * D_;  // 4M elements
  const size_t WSZ = (size_t)D_ * D_;       // 1M elements
  _Float16* ws = (_Float16*)d_ws;
  _Float16* Xf = ws;                 // 3*XSZ fp16 q,k,v inputs
  _Float16* Wt = Xf + 3 * XSZ;       // 4*WSZ fp16 W^T x4
  _Float16* Qh = Wt + 4 * WSZ;       // 3*XSZ (Qh, Kh, V^T contiguous)
  _Float16* Hd = Qh + 3 * XSZ;       // XSZ
  int* order = (int*)(Hd + XSZ);     // 32-entry LPT head order

  prep_kernel<<<dim3(6144 + 1024 + 1), 256, 0, stream>>>(
      q, k, v, Wq, Wk, Wv, Wo, vl, Xf, Wt, order);

  // fused Q/K/V projections: z selects input/weight/output.
  // z=2 writes V^T directly (transpose folded in).
  gemm_f16_kernel<4, 0><<<dim3(D_ / 128, 32, 3), 256, 0, stream>>>(
      Xf, Wt, Qh, nullptr);

  attn_kernel<<<dim3(NITEMS), 256, 0, stream>>>(
      Qh, Qh + XSZ, Qh + 2 * XSZ, vl, Hd, order);

  // output projection (BN=64 -> 512 blocks, 2/CU)
  gemm_f16_kernel<2, 1><<<dim3(D_ / 64, 32, 1), 256, 0, stream>>>(
      Hd, Wt + 3 * WSZ, nullptr, (float*)d_out);
}